// Round 7
// baseline (382.116 us; speedup 1.0000x reference)
//
#include <hip/hip_runtime.h>
#include <cmath>

#define BB 16
#define NN 1024
#define KK1 205
#define KK2 42
#define CAP 96
#define CHUNKS1 52
#define NREP 64          // BN accumulator replicas

__device__ __forceinline__ void cswap(unsigned long long& a, unsigned long long& b,
                                      bool asc) {
  unsigned long long lo = a < b ? a : b;
  unsigned long long hi = a < b ? b : a;
  a = asc ? lo : hi;
  b = asc ? hi : lo;
}
__device__ __forceinline__ unsigned long long pickmm(unsigned long long a,
                                                     unsigned long long p,
                                                     bool keepMin) {
  unsigned long long mn = a < p ? a : p;
  unsigned long long mx = a < p ? p : a;
  return keepMin ? mn : mx;
}
__device__ __forceinline__ unsigned int ordkey(float v) {
  unsigned int u = __float_as_uint(v);
  if (u == 0x80000000u) u = 0u;                    // normalize -0.0
  return (u & 0x80000000u) ? ~u : (u | 0x80000000u);
}
__device__ __forceinline__ float orddec(unsigned long long kk) {
  unsigned int ord = ~(unsigned int)(kk >> 32);
  unsigned int u = (ord & 0x80000000u) ? (ord & 0x7FFFFFFFu) : ~ord;
  return __uint_as_float(u);
}

// ------- single adj pass: degree, bitmask, neighbor list, fused x@Wd0 ------
__global__ void k_deg_csr(const float* __restrict__ adj, const float* __restrict__ x,
                          const float* __restrict__ W,
                          float* __restrict__ dis0, int* __restrict__ ncnt,
                          int* __restrict__ nbr, unsigned long long* __restrict__ mask,
                          float* __restrict__ dxw, float* __restrict__ pacc) {
  if (blockIdx.x == 0) {
    for (int q = threadIdx.x; q < NREP * 64; q += 256) pacc[q] = 0.f;
  }
  int row = blockIdx.x * 4 + (threadIdx.x >> 6);   // one wave per row
  int lane = threadIdx.x & 63;
  const float* ar = adj + (size_t)row * NN;
  float v[16];
#pragma unroll
  for (int c = 0; c < 16; ++c) v[c] = ar[c * 64 + lane];
  int base = 0;
  int* nr = nbr + (size_t)row * CAP;
#pragma unroll
  for (int c = 0; c < 16; ++c) {
    unsigned long long m = __ballot(v[c] != 0.0f);
    if (lane == c) mask[(size_t)row * 16 + c] = m;
    if (v[c] != 0.0f) {
      int pos = base + __popcll(m & ((1ull << lane) - 1ull));
      if (pos < CAP) nr[pos] = c * 64 + lane;
    }
    base += __popcll(m);
  }
  float dis = rsqrtf((float)base + 2.0f);
  if (lane == 0) {
    ncnt[row] = base < CAP ? base : CAP;
    dis0[row] = dis;
  }
  if (lane < 32) {                                  // fused dxw = dis*(x@Wd0)
    float x0 = x[row * 3], x1 = x[row * 3 + 1], x2 = x[row * 3 + 2];
    float s = x0 * W[lane] + x1 * W[32 + lane] + x2 * W[64 + lane];
    dxw[(size_t)row * 32 + lane] = s * dis;
  }
}

// ------- sparse GCN apply, LDS-staged gather source (GCN0) -----------------
__global__ __launch_bounds__(256) void k_spmm_lds(
    const float* __restrict__ dxw, const float* __restrict__ dis,
    const int* __restrict__ ncnt, const int* __restrict__ nbr,
    const float* __restrict__ bias, float* __restrict__ out,
    float* __restrict__ score, const float* __restrict__ p) {
  __shared__ float sdxw[NN * 32];                  // 128 KB
  int tid = threadIdx.x;
  int b = blockIdx.x >> 4, chunk = blockIdx.x & 15;
  {
    const float4* src = (const float4*)(dxw + ((size_t)b * NN) * 32);
    float4* dst = (float4*)sdxw;
    for (int q = tid; q < NN * 8; q += 256) dst[q] = src[q];
  }
  __syncthreads();
  int g = tid >> 5, f = tid & 31;
  float bia = bias[f];
  float pv = p[f];
#pragma unroll
  for (int it = 0; it < 8; ++it) {
    int li = chunk * 64 + g * 8 + it;
    int node = b * NN + li;
    int cnt = ncnt[node];
    const int* lst = nbr + (size_t)node * CAP;
    float a0 = 0.f, a1 = 0.f, a2 = 0.f, a3 = 0.f;
    int k = 0;
    for (; k + 4 <= cnt; k += 4) {
      int4 j4 = *(const int4*)(lst + k);
      a0 += sdxw[j4.x * 32 + f];
      a1 += sdxw[j4.y * 32 + f];
      a2 += sdxw[j4.z * 32 + f];
      a3 += sdxw[j4.w * 32 + f];
    }
    for (; k < cnt; ++k) a0 += sdxw[lst[k] * 32 + f];
    float acc = (a0 + a1) + (a2 + a3) + 2.0f * sdxw[li * 32 + f];
    float r = fmaxf(dis[node] * acc + bia, 0.f);
    out[(size_t)node * 32 + f] = r;
    float d = r * pv, pp = pv * pv;
#pragma unroll
    for (int o = 16; o; o >>= 1) { d += __shfl_xor(d, o, 32); pp += __shfl_xor(pp, o, 32); }
    if (f == 0) score[node] = tanhf(d / sqrtf(pp));
  }
}

// ------- fused final: dxw=dis*((h0+unpool(hu0))@Wu1) in LDS + spmm + BN ----
// Replaces the k_xw32u launch entirely (transform is ~2us redundant work).
__global__ __launch_bounds__(256) void k_spmm_fused(
    const float* __restrict__ h0, const float* __restrict__ hu0,
    const int* __restrict__ inv1, const float* __restrict__ Wu1,
    const float* __restrict__ dis, const int* __restrict__ ncnt,
    const int* __restrict__ nbr, const float* __restrict__ bias,
    float* __restrict__ out, float* __restrict__ pacc) {
  __shared__ float sH[NN * 32];                    // 128 KB (h0 -> dxw in place)
  __shared__ float sUp[KK1 * 32];                  // 25.6 KB (also bs/bq alias)
  __shared__ int sInv[NN];                         // 4 KB
  int tid = threadIdx.x;
  int b = blockIdx.x >> 4, chunk = blockIdx.x & 15;
  {
    const float4* src = (const float4*)(h0 + ((size_t)b * NN) * 32);
    float4* dst = (float4*)sH;
    for (int q = tid; q < NN * 8; q += 256) dst[q] = src[q];
    const float4* us = (const float4*)(hu0 + ((size_t)b * KK1) * 32);
    float4* ud = (float4*)sUp;
    for (int q = tid; q < KK1 * 8; q += 256) ud[q] = us[q];
    const int4* is = (const int4*)(inv1 + b * NN);
    ((int4*)sInv)[tid] = is[tid];
  }
  __syncthreads();
  int g = tid >> 5, f = tid & 31;
  // in-place transform: row r handled wholly by one 32-lane group (lockstep:
  // all 32 reads of the row precede the write in each lane's program order)
  for (int r = g; r < NN; r += 8) {
    int iv = sInv[r];
    float s = 0.f;
    if (iv >= 0) {
#pragma unroll
      for (int k = 0; k < 32; ++k)
        s += (sH[r * 32 + k] + sUp[iv * 32 + k]) * Wu1[k * 32 + f];
    } else {
#pragma unroll
      for (int k = 0; k < 32; ++k) s += sH[r * 32 + k] * Wu1[k * 32 + f];
    }
    s *= dis[b * NN + r];
    sH[r * 32 + f] = s;
  }
  __syncthreads();
  float bia = bias[f];
  float S = 0.f, Q = 0.f;
#pragma unroll
  for (int it = 0; it < 8; ++it) {
    int li = chunk * 64 + g * 8 + it;
    int node = b * NN + li;
    int cnt = ncnt[node];
    const int* lst = nbr + (size_t)node * CAP;
    float a0 = 0.f, a1 = 0.f, a2 = 0.f, a3 = 0.f;
    int k = 0;
    for (; k + 4 <= cnt; k += 4) {
      int4 j4 = *(const int4*)(lst + k);
      a0 += sH[j4.x * 32 + f];
      a1 += sH[j4.y * 32 + f];
      a2 += sH[j4.z * 32 + f];
      a3 += sH[j4.w * 32 + f];
    }
    for (; k < cnt; ++k) a0 += sH[lst[k] * 32 + f];
    float acc = (a0 + a1) + (a2 + a3) + 2.0f * sH[li * 32 + f];
    float r = dis[node] * acc + bia;
    out[(size_t)node * 32 + f] = r;
    S += r; Q += r * r;
  }
  // BN partials: alias bs/bq onto sUp (its reads finished pre-gather barrier)
  float* bs = sUp;            // [8][32]
  float* bq = sUp + 256;      // [8][32]
  bs[g * 32 + f] = S; bq[g * 32 + f] = Q;
  __syncthreads();
  if (tid < 32) {
    float SS = 0.f, QQ = 0.f;
#pragma unroll
    for (int q = 0; q < 8; ++q) { SS += bs[q * 32 + tid]; QQ += bq[q * 32 + tid]; }
    int rep = blockIdx.x & (NREP - 1);
    atomicAdd(&pacc[rep * 64 + tid], SS);
    atomicAdd(&pacc[rep * 64 + 32 + tid], QQ);
  }
}

// ------- fused topk1 + A1 + dis1 + t1; register/shuffle bitonic sort -------
// 4 consecutive elements per thread: j=1,2 in-register; j=4..128 via
// __shfl_xor (lane distance j/4 < 64); only j=256,512 (3 stages) touch LDS.
__global__ __launch_bounds__(256) void k_sortA1(
    const unsigned long long* __restrict__ mask, const float* __restrict__ score1,
    const float* __restrict__ h0, const float* __restrict__ Wd1,
    float* __restrict__ A1, float* __restrict__ dis1, float* __restrict__ t1,
    int* __restrict__ inv1) {
  __shared__ union {
    unsigned long long skey[1024];        // 8 KB (sort exchange)
    unsigned long long smT[16 * KK1];     // 26.2 KB (A1 phase)
  } sm;
  __shared__ int sp[KK1];
  __shared__ float sval[KK1];
  int blk = blockIdx.x;
  int b = blk / CHUNKS1, chunk = blk - b * CHUNKS1;
  int t = threadIdx.x;
  unsigned long long k0, k1, k2, k3;
  {
    const float* sc = score1 + b * NN;
    int i0 = 4 * t;
    if (chunk == 0) {
      inv1[b * NN + i0] = -1; inv1[b * NN + i0 + 1] = -1;
      inv1[b * NN + i0 + 2] = -1; inv1[b * NN + i0 + 3] = -1;
    }
    k0 = ((unsigned long long)(~ordkey(sc[i0 + 0])) << 32) | (unsigned)(i0 + 0);
    k1 = ((unsigned long long)(~ordkey(sc[i0 + 1])) << 32) | (unsigned)(i0 + 1);
    k2 = ((unsigned long long)(~ordkey(sc[i0 + 2])) << 32) | (unsigned)(i0 + 2);
    k3 = ((unsigned long long)(~ordkey(sc[i0 + 3])) << 32) | (unsigned)(i0 + 3);
  }
  cswap(k0, k1, true); cswap(k2, k3, false);        // K=2
  for (int K = 4; K <= 1024; K <<= 1) {
    bool up = ((t & (K >> 2)) == 0);
    for (int j = K >> 1; j >= 4; j >>= 1) {
      int d = j >> 2;
      bool keepMin = (((t & d) == 0) == up);
      if (d < 64) {
        unsigned long long p0 = __shfl_xor(k0, d, 64);
        unsigned long long p1 = __shfl_xor(k1, d, 64);
        unsigned long long p2 = __shfl_xor(k2, d, 64);
        unsigned long long p3 = __shfl_xor(k3, d, 64);
        k0 = pickmm(k0, p0, keepMin); k1 = pickmm(k1, p1, keepMin);
        k2 = pickmm(k2, p2, keepMin); k3 = pickmm(k3, p3, keepMin);
      } else {
        __syncthreads();
        sm.skey[4 * t + 0] = k0; sm.skey[4 * t + 1] = k1;
        sm.skey[4 * t + 2] = k2; sm.skey[4 * t + 3] = k3;
        __syncthreads();
        unsigned long long p0 = sm.skey[(4 * t + 0) ^ j];
        unsigned long long p1 = sm.skey[(4 * t + 1) ^ j];
        unsigned long long p2 = sm.skey[(4 * t + 2) ^ j];
        unsigned long long p3 = sm.skey[(4 * t + 3) ^ j];
        k0 = pickmm(k0, p0, keepMin); k1 = pickmm(k1, p1, keepMin);
        k2 = pickmm(k2, p2, keepMin); k3 = pickmm(k3, p3, keepMin);
      }
    }
    cswap(k0, k2, up); cswap(k1, k3, up);           // j=2
    cswap(k0, k1, up); cswap(k2, k3, up);           // j=1
  }
  {
    unsigned long long kk[4] = {k0, k1, k2, k3};
#pragma unroll
    for (int s = 0; s < 4; ++s) {
      int idx = 4 * t + s;
      if (idx < KK1) {
        int src = (int)(kk[s] & 0xFFFFFFFFull);
        sp[idx] = src;
        sval[idx] = orddec(kk[s]);
        if (chunk == 0) inv1[b * NN + src] = idx;
      }
    }
  }
  __syncthreads();                                  // skey reads done; reuse as smT
  for (int q = t; q < KK1 * 16; q += 256) {
    int i = q >> 4, w = q & 15;
    sm.smT[w * KK1 + i] = mask[((size_t)(b * NN + sp[i])) * 16 + w];
  }
  __syncthreads();
  int wave = t >> 6, lane = t & 63;
  int i = chunk * 4 + wave;
  if (i < KK1) {
    unsigned long long r[16];
#pragma unroll
    for (int w = 0; w < 16; ++w) r[w] = sm.smT[w * KK1 + i];
    float rowsum = 0.f;
    for (int j = lane; j < KK1; j += 64) {
      int cnt = 0;
#pragma unroll
      for (int w = 0; w < 16; ++w) cnt += __popcll(r[w] & sm.smT[w * KK1 + j]);
      int pj = sp[j];
      float edge = (float)((r[pj >> 6] >> (pj & 63)) & 1ull);
      float v = (j == i) ? 0.f : ((float)cnt + 2.f * edge);
      A1[((size_t)(b * KK1) + i) * KK1 + j] = v;
      rowsum += v;
    }
#pragma unroll
    for (int o = 32; o; o >>= 1) rowsum += __shfl_xor(rowsum, o);
    float dis = rsqrtf(rowsum + 2.0f);
    if (lane == 0) dis1[b * KK1 + i] = dis;
    if (lane < 32) {                              // t1 = dis*val*(h0[perm]@Wd1)
      const float* hr = h0 + (size_t)(b * NN + sp[i]) * 32;
      float s = 0.f;
#pragma unroll
      for (int k = 0; k < 32; ++k) s += hr[k] * Wd1[k * 32 + lane];
      t1[((size_t)(b * KK1) + i) * 32 + lane] = s * dis * sval[i];
    }
  }
}

// ------- dense GCN apply: one block per row (+opt fused pool-2 score) ------
template<bool RELU, bool SCORE>
__global__ __launch_bounds__(256) void k_dense_apply(
    const float* __restrict__ A, const float* __restrict__ tbuf,
    const float* __restrict__ dis, const float* __restrict__ bias,
    int M, float* __restrict__ out, float* __restrict__ score,
    const float* __restrict__ p) {
  int row = blockIdx.x;
  int b = row / M, i = row - b * M;
  int tid = threadIdx.x;
  int g = tid >> 5, f = tid & 31;
  const float* Ar = A + (size_t)row * M;
  const float* tb = tbuf + (size_t)b * M * 32;
  float acc = 0.f;
  for (int j = g; j < M; j += 8)
    acc += Ar[j] * tb[j * 32 + f];
  __shared__ float ls[8][32];
  ls[g][f] = acc;
  __syncthreads();
  if (tid < 32) {
    float s = 0.f;
#pragma unroll
    for (int q = 0; q < 8; ++q) s += ls[q][tid];
    s += 2.0f * tb[i * 32 + tid];
    float r = dis[row] * s + bias[tid];
    if (RELU) r = fmaxf(r, 0.f);
    out[(size_t)row * 32 + tid] = r;
    if (SCORE) {
      float pv = p[tid];
      float d = r * pv, pp = pv * pv;
#pragma unroll
      for (int o = 16; o; o >>= 1) { d += __shfl_xor(d, o, 32); pp += __shfl_xor(pp, o, 32); }
      if (tid == 0) score[row] = tanhf(d / sqrtf(pp));
    }
  }
}

// ------- buildA2 + fused redundant topk2 (shuffle bitonic, 1 elem/thread) --
__global__ __launch_bounds__(256) void k_buildA2s(
    const float* __restrict__ score2, const float* __restrict__ A1,
    const float* __restrict__ h1, const float* __restrict__ Wd2,
    float* __restrict__ A2, float* __restrict__ dis2, float* __restrict__ t2,
    int* __restrict__ inv2) {
  __shared__ unsigned long long skey[256];
  __shared__ int sp2[KK2];
  __shared__ float sv2[KK2];
  __shared__ float gsum[8];
  __shared__ float ds2s;
  int row = blockIdx.x;                            // b*KK2 + i
  int b = row / KK2, i = row - b * KK2;
  int t = threadIdx.x;
  unsigned long long key;
  {
    unsigned int ordv;
    if (t < KK1) {
      ordv = ordkey(score2[b * KK1 + t]);
      if (i == 0) inv2[b * KK1 + t] = -1;
    } else ordv = 0u;
    key = ((unsigned long long)(~ordv) << 32) | (unsigned)t;
  }
  for (int K = 2; K <= 256; K <<= 1) {
    bool up = ((t & K) == 0);
    for (int j = K >> 1; j >= 1; j >>= 1) {
      bool keepMin = (((t & j) == 0) == up);
      unsigned long long pk;
      if (j < 64) {
        pk = __shfl_xor(key, j, 64);
      } else {
        __syncthreads();
        skey[t] = key;
        __syncthreads();
        pk = skey[t ^ j];
      }
      key = pickmm(key, pk, keepMin);
    }
  }
  if (t < KK2) {
    int src = (int)(key & 0xFFFFFFFFull);
    sp2[t] = src;
    sv2[t] = orddec(key);
    if (i == 0) inv2[b * KK1 + src] = t;
  }
  __syncthreads();
  int g = t >> 5, lane = t & 31;
  int pi = sp2[i];
  const float* Ri = A1 + ((size_t)(b * KK1 + pi)) * KK1;
  float part = 0.f;
  for (int j = g; j < KK2; j += 8) {
    const float* Rj = A1 + ((size_t)(b * KK1 + sp2[j])) * KK1;
    float s = 0.f;
    for (int k = lane; k < KK1; k += 32) s += Ri[k] * Rj[k];
#pragma unroll
    for (int o = 16; o; o >>= 1) s += __shfl_xor(s, o, 32);
    float v = (i == j) ? 0.f : (s + 2.0f * Ri[sp2[j]]);
    if (lane == 0) {
      A2[(size_t)row * KK2 + j] = v;
      part += v;
    }
  }
  if (lane == 0) gsum[g] = part;
  __syncthreads();
  if (t == 0) {
    float s = 0.f;
#pragma unroll
    for (int q = 0; q < 8; ++q) s += gsum[q];
    float d2 = rsqrtf(s + 2.0f);
    dis2[row] = d2;
    ds2s = d2;
  }
  __syncthreads();
  if (t < 32) {                                    // fused t2 row
    const float* hr = h1 + (size_t)(b * KK1 + pi) * 32;
    float s = 0.f;
#pragma unroll
    for (int k = 0; k < 32; ++k) s += hr[k] * Wd2[k * 32 + t];
    t2[(size_t)row * 32 + t] = s * ds2s * sv2[i];
  }
}

// ------- t = dis * ((h + unpool(up)) @ W) ----------------------------------
__global__ void k_xw32u(const float* __restrict__ h, const float* __restrict__ up,
                        const int* __restrict__ inv, const float* __restrict__ W,
                        const float* __restrict__ dis, int M, int K,
                        float* __restrict__ out) {
  int idx = blockIdx.x * 256 + threadIdx.x;       // rows*32
  int f = idx & 31; int node = idx >> 5;          // node = b*M + i
  int b = node / M;
  int iv = inv[node];
  const float* xr = h + (size_t)node * 32;
  float s = 0.f;
  if (iv >= 0) {
    const float* ur = up + (size_t)(b * K + iv) * 32;
#pragma unroll
    for (int k = 0; k < 32; ++k) s += (xr[k] + ur[k]) * W[k * 32 + f];
  } else {
#pragma unroll
    for (int k = 0; k < 32; ++k) s += xr[k] * W[k * 32 + f];
  }
  out[idx] = s * dis[node];
}

// ------- BN (reduce NREP replica slots) + 3-layer MLP head -----------------
__global__ __launch_bounds__(64) void k_mlp(
    const float* __restrict__ h, const float* __restrict__ pacc,
    const float* __restrict__ gamma, const float* __restrict__ beta,
    const float* __restrict__ W1, const float* __restrict__ b1,
    const float* __restrict__ W2, const float* __restrict__ b2,
    const float* __restrict__ W3, const float* __restrict__ b3,
    float* __restrict__ out) {
  __shared__ float sW1[1024], sW2[1024], sW3[128];
  __shared__ float sb1[32], sb2[32], sb3[4], sscale[32], sshift[32];
  __shared__ float red[64];
  int t = threadIdx.x;
  {
    const float4* W1v = (const float4*)W1; float4* d1 = (float4*)sW1;
#pragma unroll
    for (int i = 0; i < 4; ++i) d1[t + i * 64] = W1v[t + i * 64];
    const float4* W2v = (const float4*)W2; float4* d2 = (float4*)sW2;
#pragma unroll
    for (int i = 0; i < 4; ++i) d2[t + i * 64] = W2v[t + i * 64];
    if (t < 32) ((float4*)sW3)[t] = ((const float4*)W3)[t];
    if (t < 32) { sb1[t] = b1[t]; sb2[t] = b2[t]; }
    if (t < 4) sb3[t] = b3[t];
    float a0 = 0.f, a1 = 0.f, a2 = 0.f, a3 = 0.f;
#pragma unroll
    for (int rep = 0; rep < NREP; rep += 4) {
      a0 += pacc[(rep + 0) * 64 + t]; a1 += pacc[(rep + 1) * 64 + t];
      a2 += pacc[(rep + 2) * 64 + t]; a3 += pacc[(rep + 3) * 64 + t];
    }
    red[t] = (a0 + a1) + (a2 + a3);
  }
  __syncthreads();
  if (t < 32) {
    const float inv = 1.0f / (float)(BB * NN);
    float m = red[t] * inv;
    float v = red[32 + t] * inv - m * m;
    float sc = gamma[t] * rsqrtf(v + 1e-5f);
    sscale[t] = sc;
    sshift[t] = beta[t] - m * sc;
  }
  __syncthreads();
  int node = blockIdx.x * 64 + t;
  const float4* hr = (const float4*)(h + (size_t)node * 32);
  float hn[32];
#pragma unroll
  for (int i = 0; i < 8; ++i) {
    float4 x = hr[i];
    hn[i * 4 + 0] = x.x * sscale[i * 4 + 0] + sshift[i * 4 + 0];
    hn[i * 4 + 1] = x.y * sscale[i * 4 + 1] + sshift[i * 4 + 1];
    hn[i * 4 + 2] = x.z * sscale[i * 4 + 2] + sshift[i * 4 + 2];
    hn[i * 4 + 3] = x.w * sscale[i * 4 + 3] + sshift[i * 4 + 3];
  }
  float r1[32];
#pragma unroll
  for (int f = 0; f < 32; ++f) r1[f] = sb1[f];
#pragma unroll
  for (int k = 0; k < 32; ++k) {
    float a = hn[k];
#pragma unroll
    for (int f = 0; f < 32; ++f) r1[f] += a * sW1[k * 32 + f];
  }
#pragma unroll
  for (int f = 0; f < 32; ++f) r1[f] = r1[f] > 0.f ? r1[f] : 0.01f * r1[f];
  float r2[32];
#pragma unroll
  for (int f = 0; f < 32; ++f) r2[f] = sb2[f];
#pragma unroll
  for (int k = 0; k < 32; ++k) {
    float a = r1[k];
#pragma unroll
    for (int f = 0; f < 32; ++f) r2[f] += a * sW2[k * 32 + f];
  }
#pragma unroll
  for (int f = 0; f < 32; ++f) r2[f] = r2[f] > 0.f ? r2[f] : 0.01f * r2[f];
  float r3[4];
#pragma unroll
  for (int c = 0; c < 4; ++c) r3[c] = sb3[c];
#pragma unroll
  for (int k = 0; k < 32; ++k) {
    float a = r2[k];
#pragma unroll
    for (int c = 0; c < 4; ++c) r3[c] += a * sW3[k * 4 + c];
  }
  float4 o;
  o.x = 1.0f / (1.0f + expf(-r3[0]));
  o.y = r3[1]; o.z = r3[2]; o.w = r3[3];
  ((float4*)out)[node] = o;
}

extern "C" void kernel_launch(void* const* d_in, const int* in_sizes, int n_in,
                              void* d_out, int out_size, void* d_ws, size_t ws_size,
                              hipStream_t stream) {
  const float* x    = (const float*)d_in[0];
  const float* adj  = (const float*)d_in[1];
  const float* Wd0  = (const float*)d_in[2];
  const float* bd0  = (const float*)d_in[3];
  const float* Wd1  = (const float*)d_in[4];
  const float* bd1  = (const float*)d_in[5];
  const float* Wd2  = (const float*)d_in[6];
  const float* bd2  = (const float*)d_in[7];
  const float* Wu0  = (const float*)d_in[8];
  const float* bu0  = (const float*)d_in[9];
  const float* Wu1  = (const float*)d_in[10];
  const float* bu1  = (const float*)d_in[11];
  const float* p1   = (const float*)d_in[12];
  const float* p2   = (const float*)d_in[13];
  const float* gamma= (const float*)d_in[14];
  const float* beta = (const float*)d_in[15];
  const float* W1   = (const float*)d_in[16];
  const float* b1   = (const float*)d_in[17];
  const float* W2   = (const float*)d_in[18];
  const float* b2   = (const float*)d_in[19];
  const float* W3   = (const float*)d_in[20];
  const float* b3   = (const float*)d_in[21];
  float* out = (float*)d_out;

  char* w = (char*)d_ws;
  auto alloc = [&](size_t bytes) -> void* {
    void* p = (void*)w;
    w += (bytes + 255) & ~(size_t)255;
    return p;
  };
  float* dis0 = (float*)alloc(BB * NN * 4);
  int*   ncnt = (int*)alloc(BB * NN * 4);
  int*   nbr  = (int*)alloc((size_t)BB * NN * CAP * 4);
  unsigned long long* mask = (unsigned long long*)alloc((size_t)BB * NN * 16 * 8);
  float* dxw  = (float*)alloc((size_t)BB * NN * 32 * 4);
  float* h0   = (float*)alloc((size_t)BB * NN * 32 * 4);
  float* score1 = (float*)alloc(BB * NN * 4);
  int*   inv1 = (int*)alloc(BB * NN * 4);
  float* A1   = (float*)alloc((size_t)BB * KK1 * KK1 * 4);
  float* dis1 = (float*)alloc(BB * KK1 * 4);
  float* t1   = (float*)alloc((size_t)BB * KK1 * 32 * 4);
  float* h1   = (float*)alloc((size_t)BB * KK1 * 32 * 4);
  float* score2 = (float*)alloc(BB * KK1 * 4);
  int*   inv2 = (int*)alloc(BB * KK1 * 4);
  float* A2   = (float*)alloc((size_t)BB * KK2 * KK2 * 4);
  float* dis2 = (float*)alloc(BB * KK2 * 4);
  float* t2   = (float*)alloc((size_t)BB * KK2 * 32 * 4);
  float* h2   = (float*)alloc((size_t)BB * KK2 * 32 * 4);
  float* hu0  = (float*)alloc((size_t)BB * KK1 * 32 * 4);
  float* hfin = (float*)alloc((size_t)BB * NN * 32 * 4);
  float* pacc = (float*)alloc((size_t)NREP * 64 * 4);

  const int TOT_K132 = BB * KK1 * 32;    // 104960

  // 1) adj pass: degree + bitmask + CSR + fused x@Wd0 (+zero pacc)
  k_deg_csr<<<BB * NN / 4, 256, 0, stream>>>(adj, x, Wd0, dis0, ncnt, nbr, mask, dxw, pacc);
  // 2) GCN0 apply, LDS-staged (+fused pool-1 score)
  k_spmm_lds<<<BB * 16, 256, 0, stream>>>(dxw, dis0, ncnt, nbr, bd0, h0, score1, p1);
  // 3) fused topk1 + A1 + dis1 + t1 (register/shuffle bitonic)
  k_sortA1<<<BB * CHUNKS1, 256, 0, stream>>>(mask, score1, h0, Wd1, A1, dis1, t1, inv1);
  // 4) GCN1 apply (+fused pool-2 score)
  k_dense_apply<true, true><<<BB * KK1, 256, 0, stream>>>(
      A1, t1, dis1, bd1, KK1, h1, score2, p2);
  // 5) fused topk2 + A2 row + dis2 + t2 (shuffle bitonic)
  k_buildA2s<<<BB * KK2, 256, 0, stream>>>(score2, A1, h1, Wd2, A2, dis2, t2, inv2);
  // 6) GCN2 apply → h2
  k_dense_apply<true, false><<<BB * KK2, 256, 0, stream>>>(
      A2, t2, dis2, bd2, KK2, h2, nullptr, nullptr);
  // 7) up-level-1 matmul (unpool fused via inv2)
  k_xw32u<<<TOT_K132 / 256, 256, 0, stream>>>(h1, h2, inv2, Wu0, dis1, KK1, KK2, t1);
  // 8) up-level-1 dense GCN apply → hu0
  k_dense_apply<true, false><<<BB * KK1, 256, 0, stream>>>(
      A1, t1, dis1, bu0, KK1, hu0, nullptr, nullptr);
  // 9) fused final: in-LDS unpool-matmul + sparse GCN + BN stats
  k_spmm_fused<<<BB * 16, 256, 0, stream>>>(h0, hu0, inv1, Wu1, dis0, ncnt, nbr,
                                            bu1, hfin, pacc);
  // 10) fused BN + MLP head
  k_mlp<<<BB * NN / 64, 64, 0, stream>>>(hfin, pacc, gamma, beta,
                                         W1, b1, W2, b2, W3, b3, out);
}

// Round 8
// 332.898 us; speedup vs baseline: 1.1478x; 1.1478x over previous
//
#include <hip/hip_runtime.h>
#include <cmath>

#define BB 16
#define NN 1024
#define KK1 205
#define KK2 42
#define CAP 96
#define CHUNKS1 52
#define NREP 64          // BN accumulator replicas
#define UPCH 26          // up-level-1 row chunks (26*8 >= 205)

__device__ __forceinline__ void cswap(unsigned long long& a, unsigned long long& b,
                                      bool asc) {
  unsigned long long lo = a < b ? a : b;
  unsigned long long hi = a < b ? b : a;
  a = asc ? lo : hi;
  b = asc ? hi : lo;
}
__device__ __forceinline__ unsigned long long pickmm(unsigned long long a,
                                                     unsigned long long p,
                                                     bool keepMin) {
  unsigned long long mn = a < p ? a : p;
  unsigned long long mx = a < p ? p : a;
  return keepMin ? mn : mx;
}
__device__ __forceinline__ unsigned int ordkey(float v) {
  unsigned int u = __float_as_uint(v);
  if (u == 0x80000000u) u = 0u;                    // normalize -0.0
  return (u & 0x80000000u) ? ~u : (u | 0x80000000u);
}
__device__ __forceinline__ float orddec(unsigned long long kk) {
  unsigned int ord = ~(unsigned int)(kk >> 32);
  unsigned int u = (ord & 0x80000000u) ? (ord & 0x7FFFFFFFu) : ~ord;
  return __uint_as_float(u);
}

// ------- single adj pass: degree, bitmask, neighbor list, fused x@Wd0 ------
__global__ void k_deg_csr(const float* __restrict__ adj, const float* __restrict__ x,
                          const float* __restrict__ W,
                          float* __restrict__ dis0, int* __restrict__ ncnt,
                          int* __restrict__ nbr, unsigned long long* __restrict__ mask,
                          float* __restrict__ dxw, float* __restrict__ pacc) {
  if (blockIdx.x == 0) {
    for (int q = threadIdx.x; q < NREP * 64; q += 256) pacc[q] = 0.f;
  }
  int row = blockIdx.x * 4 + (threadIdx.x >> 6);   // one wave per row
  int lane = threadIdx.x & 63;
  const float* ar = adj + (size_t)row * NN;
  float v[16];
#pragma unroll
  for (int c = 0; c < 16; ++c) v[c] = ar[c * 64 + lane];
  int base = 0;
  int* nr = nbr + (size_t)row * CAP;
#pragma unroll
  for (int c = 0; c < 16; ++c) {
    unsigned long long m = __ballot(v[c] != 0.0f);
    if (lane == c) mask[(size_t)row * 16 + c] = m;
    if (v[c] != 0.0f) {
      int pos = base + __popcll(m & ((1ull << lane) - 1ull));
      if (pos < CAP) nr[pos] = c * 64 + lane;
    }
    base += __popcll(m);
  }
  float dis = rsqrtf((float)base + 2.0f);
  if (lane == 0) {
    ncnt[row] = base < CAP ? base : CAP;
    dis0[row] = dis;
  }
  if (lane < 32) {                                  // fused dxw = dis*(x@Wd0)
    float x0 = x[row * 3], x1 = x[row * 3 + 1], x2 = x[row * 3 + 2];
    float s = x0 * W[lane] + x1 * W[32 + lane] + x2 * W[64 + lane];
    dxw[(size_t)row * 32 + lane] = s * dis;
  }
}

// ------- sparse GCN apply, LDS-staged gather source ------------------------
// 256 blocks = 16 batches x 16 chunks; each stages its batch's 128KB dxw
// slice (coalesced float4), then gathers at LDS latency. (R6-proven.)
template<bool RELU, bool SCORE, bool BNSTATS>
__global__ __launch_bounds__(256) void k_spmm_lds(
    const float* __restrict__ dxw, const float* __restrict__ dis,
    const int* __restrict__ ncnt, const int* __restrict__ nbr,
    const float* __restrict__ bias, float* __restrict__ out,
    float* __restrict__ score, const float* __restrict__ p,
    float* __restrict__ pacc) {
  __shared__ float sdxw[NN * 32];                  // 128 KB
  __shared__ float bs[8][32], bq[8][32];
  int tid = threadIdx.x;
  int b = blockIdx.x >> 4, chunk = blockIdx.x & 15;
  {
    const float4* src = (const float4*)(dxw + ((size_t)b * NN) * 32);
    float4* dst = (float4*)sdxw;
    for (int q = tid; q < NN * 8; q += 256) dst[q] = src[q];
  }
  __syncthreads();
  int g = tid >> 5, f = tid & 31;
  float bia = bias[f];
  float pv = SCORE ? p[f] : 0.f;
  float S = 0.f, Q = 0.f;
#pragma unroll
  for (int it = 0; it < 8; ++it) {
    int li = chunk * 64 + g * 8 + it;
    int node = b * NN + li;
    int cnt = ncnt[node];
    const int* lst = nbr + (size_t)node * CAP;
    float a0 = 0.f, a1 = 0.f, a2 = 0.f, a3 = 0.f;
    int k = 0;
    for (; k + 4 <= cnt; k += 4) {
      int4 j4 = *(const int4*)(lst + k);
      a0 += sdxw[j4.x * 32 + f];
      a1 += sdxw[j4.y * 32 + f];
      a2 += sdxw[j4.z * 32 + f];
      a3 += sdxw[j4.w * 32 + f];
    }
    for (; k < cnt; ++k) a0 += sdxw[lst[k] * 32 + f];
    float acc = (a0 + a1) + (a2 + a3) + 2.0f * sdxw[li * 32 + f];
    float r = dis[node] * acc + bia;
    if (RELU) r = fmaxf(r, 0.f);
    out[(size_t)node * 32 + f] = r;
    if (SCORE) {
      float d = r * pv, pp = pv * pv;
#pragma unroll
      for (int o = 16; o; o >>= 1) { d += __shfl_xor(d, o, 32); pp += __shfl_xor(pp, o, 32); }
      if (f == 0) score[node] = tanhf(d / sqrtf(pp));
    }
    if (BNSTATS) { S += r; Q += r * r; }
  }
  if (BNSTATS) {
    bs[g][f] = S; bq[g][f] = Q;
    __syncthreads();
    if (tid < 32) {
      float SS = 0.f, QQ = 0.f;
#pragma unroll
      for (int q = 0; q < 8; ++q) { SS += bs[q][tid]; QQ += bq[q][tid]; }
      int rep = blockIdx.x & (NREP - 1);
      atomicAdd(&pacc[rep * 64 + tid], SS);
      atomicAdd(&pacc[rep * 64 + 32 + tid], QQ);
    }
  }
}

// ------- fused topk1 + A1 + dis1 + t1; register/shuffle bitonic sort -------
__global__ __launch_bounds__(256) void k_sortA1(
    const unsigned long long* __restrict__ mask, const float* __restrict__ score1,
    const float* __restrict__ h0, const float* __restrict__ Wd1,
    float* __restrict__ A1, float* __restrict__ dis1, float* __restrict__ t1,
    int* __restrict__ inv1) {
  __shared__ union {
    unsigned long long skey[1024];        // 8 KB (sort exchange)
    unsigned long long smT[16 * KK1];     // 26.2 KB (A1 phase)
  } sm;
  __shared__ int sp[KK1];
  __shared__ float sval[KK1];
  int blk = blockIdx.x;
  int b = blk / CHUNKS1, chunk = blk - b * CHUNKS1;
  int t = threadIdx.x;
  unsigned long long k0, k1, k2, k3;
  {
    const float* sc = score1 + b * NN;
    int i0 = 4 * t;
    if (chunk == 0) {
      inv1[b * NN + i0] = -1; inv1[b * NN + i0 + 1] = -1;
      inv1[b * NN + i0 + 2] = -1; inv1[b * NN + i0 + 3] = -1;
    }
    k0 = ((unsigned long long)(~ordkey(sc[i0 + 0])) << 32) | (unsigned)(i0 + 0);
    k1 = ((unsigned long long)(~ordkey(sc[i0 + 1])) << 32) | (unsigned)(i0 + 1);
    k2 = ((unsigned long long)(~ordkey(sc[i0 + 2])) << 32) | (unsigned)(i0 + 2);
    k3 = ((unsigned long long)(~ordkey(sc[i0 + 3])) << 32) | (unsigned)(i0 + 3);
  }
  cswap(k0, k1, true); cswap(k2, k3, false);        // K=2
  for (int K = 4; K <= 1024; K <<= 1) {
    bool up = ((t & (K >> 2)) == 0);
    for (int j = K >> 1; j >= 4; j >>= 1) {
      int d = j >> 2;
      bool keepMin = (((t & d) == 0) == up);
      if (d < 64) {
        unsigned long long p0 = __shfl_xor(k0, d, 64);
        unsigned long long p1 = __shfl_xor(k1, d, 64);
        unsigned long long p2 = __shfl_xor(k2, d, 64);
        unsigned long long p3 = __shfl_xor(k3, d, 64);
        k0 = pickmm(k0, p0, keepMin); k1 = pickmm(k1, p1, keepMin);
        k2 = pickmm(k2, p2, keepMin); k3 = pickmm(k3, p3, keepMin);
      } else {
        __syncthreads();
        sm.skey[4 * t + 0] = k0; sm.skey[4 * t + 1] = k1;
        sm.skey[4 * t + 2] = k2; sm.skey[4 * t + 3] = k3;
        __syncthreads();
        unsigned long long p0 = sm.skey[(4 * t + 0) ^ j];
        unsigned long long p1 = sm.skey[(4 * t + 1) ^ j];
        unsigned long long p2 = sm.skey[(4 * t + 2) ^ j];
        unsigned long long p3 = sm.skey[(4 * t + 3) ^ j];
        k0 = pickmm(k0, p0, keepMin); k1 = pickmm(k1, p1, keepMin);
        k2 = pickmm(k2, p2, keepMin); k3 = pickmm(k3, p3, keepMin);
      }
    }
    cswap(k0, k2, up); cswap(k1, k3, up);           // j=2
    cswap(k0, k1, up); cswap(k2, k3, up);           // j=1
  }
  {
    unsigned long long kk[4] = {k0, k1, k2, k3};
#pragma unroll
    for (int s = 0; s < 4; ++s) {
      int idx = 4 * t + s;
      if (idx < KK1) {
        int src = (int)(kk[s] & 0xFFFFFFFFull);
        sp[idx] = src;
        sval[idx] = orddec(kk[s]);
        if (chunk == 0) inv1[b * NN + src] = idx;
      }
    }
  }
  __syncthreads();
  for (int q = t; q < KK1 * 16; q += 256) {
    int i = q >> 4, w = q & 15;
    sm.smT[w * KK1 + i] = mask[((size_t)(b * NN + sp[i])) * 16 + w];
  }
  __syncthreads();
  int wave = t >> 6, lane = t & 63;
  int i = chunk * 4 + wave;
  if (i < KK1) {
    unsigned long long r[16];
#pragma unroll
    for (int w = 0; w < 16; ++w) r[w] = sm.smT[w * KK1 + i];
    float rowsum = 0.f;
    for (int j = lane; j < KK1; j += 64) {
      int cnt = 0;
#pragma unroll
      for (int w = 0; w < 16; ++w) cnt += __popcll(r[w] & sm.smT[w * KK1 + j]);
      int pj = sp[j];
      float edge = (float)((r[pj >> 6] >> (pj & 63)) & 1ull);
      float v = (j == i) ? 0.f : ((float)cnt + 2.f * edge);
      A1[((size_t)(b * KK1) + i) * KK1 + j] = v;
      rowsum += v;
    }
#pragma unroll
    for (int o = 32; o; o >>= 1) rowsum += __shfl_xor(rowsum, o);
    float dis = rsqrtf(rowsum + 2.0f);
    if (lane == 0) dis1[b * KK1 + i] = dis;
    if (lane < 32) {                              // t1 = dis*val*(h0[perm]@Wd1)
      const float* hr = h0 + (size_t)(b * NN + sp[i]) * 32;
      float s = 0.f;
#pragma unroll
      for (int k = 0; k < 32; ++k) s += hr[k] * Wd1[k * 32 + lane];
      t1[((size_t)(b * KK1) + i) * 32 + lane] = s * dis * sval[i];
    }
  }
}

// ------- dense GCN apply: one block per row (+opt fused pool-2 score) ------
template<bool RELU, bool SCORE>
__global__ __launch_bounds__(256) void k_dense_apply(
    const float* __restrict__ A, const float* __restrict__ tbuf,
    const float* __restrict__ dis, const float* __restrict__ bias,
    int M, float* __restrict__ out, float* __restrict__ score,
    const float* __restrict__ p) {
  int row = blockIdx.x;
  int b = row / M, i = row - b * M;
  int tid = threadIdx.x;
  int g = tid >> 5, f = tid & 31;
  const float* Ar = A + (size_t)row * M;
  const float* tb = tbuf + (size_t)b * M * 32;
  float acc = 0.f;
  for (int j = g; j < M; j += 8)
    acc += Ar[j] * tb[j * 32 + f];
  __shared__ float ls[8][32];
  ls[g][f] = acc;
  __syncthreads();
  if (tid < 32) {
    float s = 0.f;
#pragma unroll
    for (int q = 0; q < 8; ++q) s += ls[q][tid];
    s += 2.0f * tb[i * 32 + tid];
    float r = dis[row] * s + bias[tid];
    if (RELU) r = fmaxf(r, 0.f);
    out[(size_t)row * 32 + tid] = r;
    if (SCORE) {
      float pv = p[tid];
      float d = r * pv, pp = pv * pv;
#pragma unroll
      for (int o = 16; o; o >>= 1) { d += __shfl_xor(d, o, 32); pp += __shfl_xor(pp, o, 32); }
      if (tid == 0) score[row] = tanhf(d / sqrtf(pp));
    }
  }
}

// ------- buildA2 + fused redundant topk2 (shuffle bitonic, 1 elem/thread) --
__global__ __launch_bounds__(256) void k_buildA2s(
    const float* __restrict__ score2, const float* __restrict__ A1,
    const float* __restrict__ h1, const float* __restrict__ Wd2,
    float* __restrict__ A2, float* __restrict__ dis2, float* __restrict__ t2,
    int* __restrict__ inv2) {
  __shared__ unsigned long long skey[256];
  __shared__ int sp2[KK2];
  __shared__ float sv2[KK2];
  __shared__ float gsum[8];
  __shared__ float ds2s;
  int row = blockIdx.x;                            // b*KK2 + i
  int b = row / KK2, i = row - b * KK2;
  int t = threadIdx.x;
  unsigned long long key;
  {
    unsigned int ordv;
    if (t < KK1) {
      ordv = ordkey(score2[b * KK1 + t]);
      if (i == 0) inv2[b * KK1 + t] = -1;
    } else ordv = 0u;
    key = ((unsigned long long)(~ordv) << 32) | (unsigned)t;
  }
  for (int K = 2; K <= 256; K <<= 1) {
    bool up = ((t & K) == 0);
    for (int j = K >> 1; j >= 1; j >>= 1) {
      bool keepMin = (((t & j) == 0) == up);
      unsigned long long pk;
      if (j < 64) {
        pk = __shfl_xor(key, j, 64);
      } else {
        __syncthreads();
        skey[t] = key;
        __syncthreads();
        pk = skey[t ^ j];
      }
      key = pickmm(key, pk, keepMin);
    }
  }
  if (t < KK2) {
    int src = (int)(key & 0xFFFFFFFFull);
    sp2[t] = src;
    sv2[t] = orddec(key);
    if (i == 0) inv2[b * KK1 + src] = t;
  }
  __syncthreads();
  int g = t >> 5, lane = t & 31;
  int pi = sp2[i];
  const float* Ri = A1 + ((size_t)(b * KK1 + pi)) * KK1;
  float part = 0.f;
  for (int j = g; j < KK2; j += 8) {
    const float* Rj = A1 + ((size_t)(b * KK1 + sp2[j])) * KK1;
    float s = 0.f;
    for (int k = lane; k < KK1; k += 32) s += Ri[k] * Rj[k];
#pragma unroll
    for (int o = 16; o; o >>= 1) s += __shfl_xor(s, o, 32);
    float v = (i == j) ? 0.f : (s + 2.0f * Ri[sp2[j]]);
    if (lane == 0) {
      A2[(size_t)row * KK2 + j] = v;
      part += v;
    }
  }
  if (lane == 0) gsum[g] = part;
  __syncthreads();
  if (t == 0) {
    float s = 0.f;
#pragma unroll
    for (int q = 0; q < 8; ++q) s += gsum[q];
    float d2 = rsqrtf(s + 2.0f);
    dis2[row] = d2;
    ds2s = d2;
  }
  __syncthreads();
  if (t < 32) {                                    // fused t2 row
    const float* hr = h1 + (size_t)(b * KK1 + pi) * 32;
    float s = 0.f;
#pragma unroll
    for (int k = 0; k < 32; ++k) s += hr[k] * Wd2[k * 32 + t];
    t2[(size_t)row * 32 + t] = s * ds2s * sv2[i];
  }
}

// ------- fused up-level-1: t1' (in LDS) + dense GCN apply → hu0 ------------
// 416 blocks = 16 batches x 26 row-chunks of 8. Each block stages h1/h2/inv2
// (32 KB) + computes t1' for ALL 205 rows in LDS (~820 FMA/thread, bounded
// redundancy x26), then each 32-lane group applies ONE A1 row. 62 KB LDS ->
// 2 blocks/CU (the spmm_fused mistake was 1M MACs + 1 block/CU).
__global__ __launch_bounds__(256) void k_up1w(
    const float* __restrict__ h1, const float* __restrict__ h2,
    const int* __restrict__ inv2, const float* __restrict__ Wu0,
    const float* __restrict__ A1, const float* __restrict__ dis1,
    const float* __restrict__ bu0, float* __restrict__ hu0) {
  __shared__ float h1s[KK1 * 32];    // 26.2 KB
  __shared__ float h2s[KK2 * 32];    // 5.3 KB
  __shared__ float st1[KK1 * 32];    // 26.2 KB
  __shared__ float wu0s[1024];       // 4 KB
  __shared__ int sinv[KK1];
  int blk = blockIdx.x;
  int b = blk / UPCH, chunk = blk - b * UPCH;
  int t = threadIdx.x;
  {
    const float4* s1 = (const float4*)(h1 + (size_t)b * KK1 * 32);
    float4* d1 = (float4*)h1s;
    for (int q = t; q < KK1 * 8; q += 256) d1[q] = s1[q];
    const float4* s2 = (const float4*)(h2 + (size_t)b * KK2 * 32);
    float4* d2 = (float4*)h2s;
    for (int q = t; q < KK2 * 8; q += 256) d2[q] = s2[q];
    ((float4*)wu0s)[t] = ((const float4*)Wu0)[t];
    if (t < KK1) sinv[t] = inv2[b * KK1 + t];
  }
  __syncthreads();
  int g = t >> 5, f = t & 31;
  for (int r = g; r < KK1; r += 8) {               // t1' all rows
    int iv = sinv[r];
    float s = 0.f;
    if (iv >= 0) {
#pragma unroll
      for (int k = 0; k < 32; ++k)
        s += (h1s[r * 32 + k] + h2s[iv * 32 + k]) * wu0s[k * 32 + f];
    } else {
#pragma unroll
      for (int k = 0; k < 32; ++k) s += h1s[r * 32 + k] * wu0s[k * 32 + f];
    }
    st1[r * 32 + f] = s * dis1[b * KK1 + r];
  }
  __syncthreads();
  int row = chunk * 8 + g;                         // one A1 row per group
  if (row < KK1) {
    const float* Ar = A1 + ((size_t)(b * KK1) + row) * KK1;
    float a0 = 0.f, a1 = 0.f, a2 = 0.f, a3 = 0.f;
    int j = 0;
    for (; j + 4 <= KK1; j += 4) {
      a0 += Ar[j + 0] * st1[(j + 0) * 32 + f];
      a1 += Ar[j + 1] * st1[(j + 1) * 32 + f];
      a2 += Ar[j + 2] * st1[(j + 2) * 32 + f];
      a3 += Ar[j + 3] * st1[(j + 3) * 32 + f];
    }
    for (; j < KK1; ++j) a0 += Ar[j] * st1[j * 32 + f];
    float acc = (a0 + a1) + (a2 + a3) + 2.0f * st1[row * 32 + f];
    float r = dis1[b * KK1 + row] * acc + bu0[f];
    hu0[((size_t)(b * KK1) + row) * 32 + f] = fmaxf(r, 0.f);
  }
}

// ------- t = dis * ((h + unpool(up)) @ W) ----------------------------------
__global__ void k_xw32u(const float* __restrict__ h, const float* __restrict__ up,
                        const int* __restrict__ inv, const float* __restrict__ W,
                        const float* __restrict__ dis, int M, int K,
                        float* __restrict__ out) {
  int idx = blockIdx.x * 256 + threadIdx.x;       // rows*32
  int f = idx & 31; int node = idx >> 5;          // node = b*M + i
  int b = node / M;
  int iv = inv[node];
  const float* xr = h + (size_t)node * 32;
  float s = 0.f;
  if (iv >= 0) {
    const float* ur = up + (size_t)(b * K + iv) * 32;
#pragma unroll
    for (int k = 0; k < 32; ++k) s += (xr[k] + ur[k]) * W[k * 32 + f];
  } else {
#pragma unroll
    for (int k = 0; k < 32; ++k) s += xr[k] * W[k * 32 + f];
  }
  out[idx] = s * dis[node];
}

// ------- BN (reduce NREP replica slots) + 3-layer MLP head -----------------
__global__ __launch_bounds__(64) void k_mlp(
    const float* __restrict__ h, const float* __restrict__ pacc,
    const float* __restrict__ gamma, const float* __restrict__ beta,
    const float* __restrict__ W1, const float* __restrict__ b1,
    const float* __restrict__ W2, const float* __restrict__ b2,
    const float* __restrict__ W3, const float* __restrict__ b3,
    float* __restrict__ out) {
  __shared__ float sW1[1024], sW2[1024], sW3[128];
  __shared__ float sb1[32], sb2[32], sb3[4], sscale[32], sshift[32];
  __shared__ float red[64];
  int t = threadIdx.x;
  {
    const float4* W1v = (const float4*)W1; float4* d1 = (float4*)sW1;
#pragma unroll
    for (int i = 0; i < 4; ++i) d1[t + i * 64] = W1v[t + i * 64];
    const float4* W2v = (const float4*)W2; float4* d2 = (float4*)sW2;
#pragma unroll
    for (int i = 0; i < 4; ++i) d2[t + i * 64] = W2v[t + i * 64];
    if (t < 32) ((float4*)sW3)[t] = ((const float4*)W3)[t];
    if (t < 32) { sb1[t] = b1[t]; sb2[t] = b2[t]; }
    if (t < 4) sb3[t] = b3[t];
    float a0 = 0.f, a1 = 0.f, a2 = 0.f, a3 = 0.f;
#pragma unroll
    for (int rep = 0; rep < NREP; rep += 4) {
      a0 += pacc[(rep + 0) * 64 + t]; a1 += pacc[(rep + 1) * 64 + t];
      a2 += pacc[(rep + 2) * 64 + t]; a3 += pacc[(rep + 3) * 64 + t];
    }
    red[t] = (a0 + a1) + (a2 + a3);
  }
  __syncthreads();
  if (t < 32) {
    const float inv = 1.0f / (float)(BB * NN);
    float m = red[t] * inv;
    float v = red[32 + t] * inv - m * m;
    float sc = gamma[t] * rsqrtf(v + 1e-5f);
    sscale[t] = sc;
    sshift[t] = beta[t] - m * sc;
  }
  __syncthreads();
  int node = blockIdx.x * 64 + t;
  const float4* hr = (const float4*)(h + (size_t)node * 32);
  float hn[32];
#pragma unroll
  for (int i = 0; i < 8; ++i) {
    float4 x = hr[i];
    hn[i * 4 + 0] = x.x * sscale[i * 4 + 0] + sshift[i * 4 + 0];
    hn[i * 4 + 1] = x.y * sscale[i * 4 + 1] + sshift[i * 4 + 1];
    hn[i * 4 + 2] = x.z * sscale[i * 4 + 2] + sshift[i * 4 + 2];
    hn[i * 4 + 3] = x.w * sscale[i * 4 + 3] + sshift[i * 4 + 3];
  }
  float r1[32];
#pragma unroll
  for (int f = 0; f < 32; ++f) r1[f] = sb1[f];
#pragma unroll
  for (int k = 0; k < 32; ++k) {
    float a = hn[k];
#pragma unroll
    for (int f = 0; f < 32; ++f) r1[f] += a * sW1[k * 32 + f];
  }
#pragma unroll
  for (int f = 0; f < 32; ++f) r1[f] = r1[f] > 0.f ? r1[f] : 0.01f * r1[f];
  float r2[32];
#pragma unroll
  for (int f = 0; f < 32; ++f) r2[f] = sb2[f];
#pragma unroll
  for (int k = 0; k < 32; ++k) {
    float a = r1[k];
#pragma unroll
    for (int f = 0; f < 32; ++f) r2[f] += a * sW2[k * 32 + f];
  }
#pragma unroll
  for (int f = 0; f < 32; ++f) r2[f] = r2[f] > 0.f ? r2[f] : 0.01f * r2[f];
  float r3[4];
#pragma unroll
  for (int c = 0; c < 4; ++c) r3[c] = sb3[c];
#pragma unroll
  for (int k = 0; k < 32; ++k) {
    float a = r2[k];
#pragma unroll
    for (int c = 0; c < 4; ++c) r3[c] += a * sW3[k * 4 + c];
  }
  float4 o;
  o.x = 1.0f / (1.0f + expf(-r3[0]));
  o.y = r3[1]; o.z = r3[2]; o.w = r3[3];
  ((float4*)out)[node] = o;
}

extern "C" void kernel_launch(void* const* d_in, const int* in_sizes, int n_in,
                              void* d_out, int out_size, void* d_ws, size_t ws_size,
                              hipStream_t stream) {
  const float* x    = (const float*)d_in[0];
  const float* adj  = (const float*)d_in[1];
  const float* Wd0  = (const float*)d_in[2];
  const float* bd0  = (const float*)d_in[3];
  const float* Wd1  = (const float*)d_in[4];
  const float* bd1  = (const float*)d_in[5];
  const float* Wd2  = (const float*)d_in[6];
  const float* bd2  = (const float*)d_in[7];
  const float* Wu0  = (const float*)d_in[8];
  const float* bu0  = (const float*)d_in[9];
  const float* Wu1  = (const float*)d_in[10];
  const float* bu1  = (const float*)d_in[11];
  const float* p1   = (const float*)d_in[12];
  const float* p2   = (const float*)d_in[13];
  const float* gamma= (const float*)d_in[14];
  const float* beta = (const float*)d_in[15];
  const float* W1   = (const float*)d_in[16];
  const float* b1   = (const float*)d_in[17];
  const float* W2   = (const float*)d_in[18];
  const float* b2   = (const float*)d_in[19];
  const float* W3   = (const float*)d_in[20];
  const float* b3   = (const float*)d_in[21];
  float* out = (float*)d_out;

  char* w = (char*)d_ws;
  auto alloc = [&](size_t bytes) -> void* {
    void* p = (void*)w;
    w += (bytes + 255) & ~(size_t)255;
    return p;
  };
  float* dis0 = (float*)alloc(BB * NN * 4);
  int*   ncnt = (int*)alloc(BB * NN * 4);
  int*   nbr  = (int*)alloc((size_t)BB * NN * CAP * 4);
  unsigned long long* mask = (unsigned long long*)alloc((size_t)BB * NN * 16 * 8);
  float* dxw  = (float*)alloc((size_t)BB * NN * 32 * 4);
  float* h0   = (float*)alloc((size_t)BB * NN * 32 * 4);
  float* score1 = (float*)alloc(BB * NN * 4);
  int*   inv1 = (int*)alloc(BB * NN * 4);
  float* A1   = (float*)alloc((size_t)BB * KK1 * KK1 * 4);
  float* dis1 = (float*)alloc(BB * KK1 * 4);
  float* t1   = (float*)alloc((size_t)BB * KK1 * 32 * 4);
  float* h1   = (float*)alloc((size_t)BB * KK1 * 32 * 4);
  float* score2 = (float*)alloc(BB * KK1 * 4);
  int*   inv2 = (int*)alloc(BB * KK1 * 4);
  float* A2   = (float*)alloc((size_t)BB * KK2 * KK2 * 4);
  float* dis2 = (float*)alloc(BB * KK2 * 4);
  float* t2   = (float*)alloc((size_t)BB * KK2 * 32 * 4);
  float* h2   = (float*)alloc((size_t)BB * KK2 * 32 * 4);
  float* hu0  = (float*)alloc((size_t)BB * KK1 * 32 * 4);
  float* hfin = (float*)alloc((size_t)BB * NN * 32 * 4);
  float* pacc = (float*)alloc((size_t)NREP * 64 * 4);

  const int TOT_N32 = BB * NN * 32;      // 524288

  // 1) adj pass: degree + bitmask + CSR + fused x@Wd0 (+zero pacc)
  k_deg_csr<<<BB * NN / 4, 256, 0, stream>>>(adj, x, Wd0, dis0, ncnt, nbr, mask, dxw, pacc);
  // 2) GCN0 apply, LDS-staged (+fused pool-1 score)
  k_spmm_lds<true, true, false><<<BB * 16, 256, 0, stream>>>(
      dxw, dis0, ncnt, nbr, bd0, h0, score1, p1, nullptr);
  // 3) fused topk1 + A1 + dis1 + t1 (register/shuffle bitonic)
  k_sortA1<<<BB * CHUNKS1, 256, 0, stream>>>(mask, score1, h0, Wd1, A1, dis1, t1, inv1);
  // 4) GCN1 apply (+fused pool-2 score)
  k_dense_apply<true, true><<<BB * KK1, 256, 0, stream>>>(
      A1, t1, dis1, bd1, KK1, h1, score2, p2);
  // 5) fused topk2 + A2 row + dis2 + t2 (shuffle bitonic)
  k_buildA2s<<<BB * KK2, 256, 0, stream>>>(score2, A1, h1, Wd2, A2, dis2, t2, inv2);
  // 6) GCN2 apply → h2
  k_dense_apply<true, false><<<BB * KK2, 256, 0, stream>>>(
      A2, t2, dis2, bd2, KK2, h2, nullptr, nullptr);
  // 7) fused up-level-1: t1' in LDS + dense apply → hu0
  k_up1w<<<BB * UPCH, 256, 0, stream>>>(h1, h2, inv2, Wu0, A1, dis1, bu0, hu0);
  // 8) final unpool matmul → dxw
  k_xw32u<<<TOT_N32 / 256, 256, 0, stream>>>(h0, hu0, inv1, Wu1, dis0, NN, KK1, dxw);
  // 9) final sparse GCN, LDS-staged (+replicated BN stats) → hfin
  k_spmm_lds<false, false, true><<<BB * 16, 256, 0, stream>>>(
      dxw, dis0, ncnt, nbr, bu1, hfin, nullptr, nullptr, pacc);
  // 10) fused BN + MLP head
  k_mlp<<<BB * NN / 64, 64, 0, stream>>>(hfin, pacc, gamma, beta,
                                         W1, b1, W2, b2, W3, b3, out);
}